// Round 11
// baseline (121.539 us; speedup 1.0000x reference)
//
#include <hip/hip_runtime.h>

#define BATCH 524288

typedef __bf16 bf16x8 __attribute__((ext_vector_type(8)));
typedef __bf16 bf16x2 __attribute__((ext_vector_type(2)));
typedef float f32x4 __attribute__((ext_vector_type(4)));
typedef float f32x8 __attribute__((ext_vector_type(8)));
typedef float f32x2 __attribute__((ext_vector_type(2)));

// LDS layout identical to v10 (verified):
//   sA2  @     0: 16384 B  A2, chunk(kk)*1024 + lane*16 (lane-consecutive, conflict-free)
//   sW1f @ 16384:  4096 B  W1 frags chunk(t, q*16+c), q<2; +32 B zero chunk @ 20480
//   sW2f @ 20512:  8192 B  W2 permuted frags, chunk(t2*4+s)*1024 + lane*16
//   sB2  @ 28704:   128 B  b2 f32;  sXT @ 28832: 64 B x_target f32
//   hcw  @ 28896 + wave*2560 + t01*1280: 16 x 40 bf16 (packed-b32 writes, 2/bank free)
#define SW1 16384
#define SZC 20480
#define SW2 20512
#define SB2 28704
#define SXT 28832
#define SHC 28896
#define SMEM_BYTES (28896 + 4 * 2560)   // 39136 B -> 4 blocks/CU

__device__ __forceinline__ f32x8 load8(const float* __restrict__ p) {
    float4 a = *(const float4*)p;
    float4 b = *(const float4*)(p + 4);
    f32x8 v = {a.x, a.y, a.z, a.w, b.x, b.y, b.z, b.w};
    return v;
}

__device__ __forceinline__ int pack2bf(float a, float b) {
    f32x2 v = {a, b};
    bf16x2 p = __builtin_convertvector(v, bf16x2);
    return __builtin_bit_cast(int, p);
}

__global__ __launch_bounds__(256, 4) void andp_v11(
    const float* __restrict__ x_cur,
    const float* __restrict__ W1,
    const float* __restrict__ b1,
    const float* __restrict__ W2,
    const float* __restrict__ b2,
    const float* __restrict__ Bm,
    const float* __restrict__ Cm,
    const float* __restrict__ x_t,
    float* __restrict__ out)
{
    extern __shared__ char smem[];
    int* sA2i = (int*)smem;
    int* sW1i = (int*)(smem + SW1);
    int* sW2i = (int*)(smem + SW2);
    const int tid = threadIdx.x;

    // ---- staging: identical to v10 (verified) ----
#pragma unroll
    for (int i = 0; i < 16; ++i) {
        int o2 = tid + i * 256;
        int o  = o2 * 2;
        int kk = o >> 9, qp = (o >> 7) & 3, k = (o >> 3) & 15, j = o & 7;
        int n = 2 * kk + (qp >> 1), d = (qp & 1) * 8 + j;
        int src = n * 256 + k * 16 + d;
        float2 bv = *(const float2*)(Bm + src);
        float2 cv = *(const float2*)(Cm + src);
        sA2i[o2] = pack2bf(bv.x + cv.x, bv.y + cv.y);
    }
#pragma unroll
    for (int i = 0; i < 4; ++i) {
        int o2 = tid + i * 256;
        int o  = o2 * 2;
        int t = o >> 8, qq = (o >> 7) & 1, cc = (o >> 3) & 15, j = o & 7;
        int src = (t * 16 + cc) * 16 + qq * 8 + j;
        float2 v = *(const float2*)(W1 + src);
        sW1i[o2] = pack2bf(v.x, v.y);
    }
    if (tid < 8) ((int*)(smem + SZC))[tid] = 0;
#pragma unroll
    for (int i = 0; i < 8; ++i) {
        int o2 = tid + i * 256;
        int chunk = o2 >> 8, rem = o2 & 255;
        int ln = rem >> 2, j2 = rem & 3;
        int qq = ln >> 4, cc = ln & 15;
        int t2 = chunk >> 2, s = chunk & 3;
        int src = (t2 * 16 + cc) * 128 + s * 32 + 4 * qq + j2;
        sW2i[o2] = pack2bf(W2[src], W2[src + 16]);
    }
    if (tid < 32) ((float*)(smem + SB2))[tid] = b2[tid];
    if (tid < 16) ((float*)(smem + SXT))[tid] = x_t[tid];

    const int wave = tid >> 6, lane = tid & 63;
    const int c = lane & 15, q = lane >> 4;
    const int qh = q >> 1;
    const int hh = (q & 1) * 8;
    const int c4 = c * 4;

    const char* sW1f = smem + SW1;
    const int w1base = (q < 2) ? ((q * 16 + c) * 16) : (SZC - SW1);
    const int w1step = (q < 2) ? 512 : 0;
    const char* sW2f = smem + SW2 + lane * 16;
    __bf16* hcw0 = (__bf16*)(smem + SHC + wave * 2560);
    __bf16* hcw1 = hcw0 + 640;
    const float* sB2f = (const float*)(smem + SB2);
    const float* sXTf = (const float*)(smem + SXT);

    float b1v[8];
#pragma unroll
    for (int t = 0; t < 8; ++t) b1v[t] = b1[t * 16 + c];

    __syncthreads();

    const int blk_row = blockIdx.x * 256 + wave * 64;
    const f32x4 z4 = {0.f, 0.f, 0.f, 0.f};

#pragma unroll 1
    for (int p = 0; p < 2; ++p) {
        const int r0 = blk_row + p * 32;

        // ---- x -> bf16 A-frag (dif reconstructed later, v10-verified) ----
        bf16x8 af[2];
#pragma unroll
        for (int t01 = 0; t01 < 2; ++t01) {
            f32x8 xv = load8(x_cur + (size_t)(r0 + t01 * 16 + c) * 16 + hh);
            af[t01] = __builtin_convertvector(xv, bf16x8);
        }

        // ---- bias C-init for G2 accumulators ----
        f32x4 bq0 = *(const f32x4*)(sB2f + q * 4);
        f32x4 bq1 = *(const f32x4*)(sB2f + 16 + q * 4);
        f32x4 acc2[2][2];
        acc2[0][0] = bq0; acc2[0][1] = bq1;
        acc2[1][0] = bq0; acc2[1][1] = bq1;

        // ---- G1/G2 software-pipelined: G2 runs one s-step behind G1 ----
        bf16x8 hbp[2];   // h chunk regs, read at bottom of iter s, consumed iter s+1
#pragma unroll
        for (int s = 0; s < 4; ++s) {
            // issue w2(s-1) reads early (consumed mid-iter by G2)
            bf16x8 w2a, w2b;
            if (s > 0) {
                w2a = *(const bf16x8*)(sW2f + (s - 1) * 1024);
                w2b = *(const bf16x8*)(sW2f + (4 + s - 1) * 1024);
            }
            // G1 MFMAs (w1 frags shared across t01)
            bf16x8 w1a = *(const bf16x8*)(sW1f + w1base + (2 * s) * w1step);
            bf16x8 w1b = *(const bf16x8*)(sW1f + w1base + (2 * s + 1) * w1step);
            f32x4 a1[2][2];
#pragma unroll
            for (int t01 = 0; t01 < 2; ++t01) {
                a1[t01][0] = __builtin_amdgcn_mfma_f32_16x16x32_bf16(af[t01], w1a, z4, 0, 0, 0);
                a1[t01][1] = __builtin_amdgcn_mfma_f32_16x16x32_bf16(af[t01], w1b, z4, 0, 0, 0);
            }
            // G2 for slice s-1 (h data arrived during G1 above)
            if (s > 0) {
#pragma unroll
                for (int t01 = 0; t01 < 2; ++t01) {
                    acc2[t01][0] = __builtin_amdgcn_mfma_f32_16x16x32_bf16(w2a, hbp[t01], acc2[t01][0], 0, 0, 0);
                    acc2[t01][1] = __builtin_amdgcn_mfma_f32_16x16x32_bf16(w2b, hbp[t01], acc2[t01][1], 0, 0, 0);
                }
            }
            // epilogue + packed-b32 h writes (v10-verified layout)
#pragma unroll
            for (int t01 = 0; t01 < 2; ++t01) {
                __bf16* hcw = t01 ? hcw1 : hcw0;
#pragma unroll
                for (int r = 0; r < 4; ++r) {
                    float va = fmaxf(a1[t01][0][r] + b1v[2 * s], 0.f);
                    float vb = fmaxf(a1[t01][1][r] + b1v[2 * s + 1], 0.f);
                    *(int*)(hcw + (q * 4 + r) * 40 + 2 * c) = pack2bf(va, vb);
                }
            }
            // issue h(s) reads; consumed next iter (RAW safe: DS is in-order per wave)
            hbp[0] = *(const bf16x8*)(hcw0 + c * 40 + q * 8);
            hbp[1] = *(const bf16x8*)(hcw1 + c * 40 + q * 8);
        }
        // drain: G2 for slice 3
        {
            bf16x8 w2a = *(const bf16x8*)(sW2f + 3 * 1024);
            bf16x8 w2b = *(const bf16x8*)(sW2f + 7 * 1024);
#pragma unroll
            for (int t01 = 0; t01 < 2; ++t01) {
                acc2[t01][0] = __builtin_amdgcn_mfma_f32_16x16x32_bf16(w2a, hbp[t01], acc2[t01][0], 0, 0, 0);
                acc2[t01][1] = __builtin_amdgcn_mfma_f32_16x16x32_bf16(w2b, hbp[t01], acc2[t01][1], 0, 0, 0);
            }
        }

        // ---- softmax, t01-fused (bias already in acc2; independent shfl chains) ----
        int wq[8];
        {
            float e0[8], e1[8];
            float s0 = 0.f, s1 = 0.f;
#pragma unroll
            for (int t2 = 0; t2 < 2; ++t2)
#pragma unroll
                for (int r = 0; r < 4; ++r) {
                    e0[t2 * 4 + r] = __expf(acc2[0][t2][r]);
                    e1[t2 * 4 + r] = __expf(acc2[1][t2][r]);
                    s0 += e0[t2 * 4 + r];
                    s1 += e1[t2 * 4 + r];
                }
            s0 += __shfl_xor(s0, 16, 64);
            s1 += __shfl_xor(s1, 16, 64);
            s0 += __shfl_xor(s0, 32, 64);
            s1 += __shfl_xor(s1, 32, 64);
            float i0 = 1.0f / s0, i1 = 1.0f / s1;
#pragma unroll
            for (int i = 0; i < 8; ++i)
                wq[i] = pack2bf(e0[i] * i0, e1[i] * i1);
        }

        // ---- reconstruct dif (v10-verified) ----
        f32x8 dif[2];
        {
            f32x4 xta = *(const f32x4*)(sXTf + hh);
            f32x4 xtb = *(const f32x4*)(sXTf + hh + 4);
            f32x8 xtv = {xta[0], xta[1], xta[2], xta[3], xtb[0], xtb[1], xtb[2], xtb[3]};
            dif[0] = xtv - __builtin_convertvector(af[0], f32x8);
            dif[1] = xtv - __builtin_convertvector(af[1], f32x8);
        }

        // ---- G3 with 1-deep prefetch on bpermute + a2f (v8-verified gate fetch) ----
        f32x4 acc3[2];
        acc3[0] = z4; acc3[1] = z4;
        int bpA = __builtin_amdgcn_ds_bpermute(c4 + 0, wq[0]);
        int bpB = __builtin_amdgcn_ds_bpermute(c4 + 0, wq[1]);
        bf16x8 a2c = *(const bf16x8*)(smem + 0 * 1024 + lane * 16);
#pragma unroll
        for (int kk = 0; kk < 16; ++kk) {
            int selv = qh ? bpB : bpA;
            bf16x8 a2u = a2c;
            if (kk < 15) {
                const int lo = ((kk + 1) >> 3) * 4 + 2 * ((kk + 1) & 1);
                const int bpi = c4 + (((kk + 1) >> 1) & 3) * 64;
                bpA = __builtin_amdgcn_ds_bpermute(bpi, wq[lo]);
                bpB = __builtin_amdgcn_ds_bpermute(bpi, wq[lo + 1]);
                a2c = *(const bf16x8*)(smem + (kk + 1) * 1024 + lane * 16);
            }
            float w0 = __builtin_bit_cast(float, (unsigned)selv << 16);
            float w1 = __builtin_bit_cast(float, (unsigned)selv & 0xffff0000u);
            bf16x8 g0 = __builtin_convertvector(dif[0] * w0, bf16x8);
            bf16x8 g1 = __builtin_convertvector(dif[1] * w1, bf16x8);
            acc3[0] = __builtin_amdgcn_mfma_f32_16x16x32_bf16(a2u, g0, acc3[0], 0, 0, 0);
            acc3[1] = __builtin_amdgcn_mfma_f32_16x16x32_bf16(a2u, g1, acc3[1], 0, 0, 0);
        }

        // ---- store (v5-verified): D[m=k_out=q*4+r][n=row=c] ----
#pragma unroll
        for (int t01 = 0; t01 < 2; ++t01) {
            float4 st = make_float4(acc3[t01][0], acc3[t01][1], acc3[t01][2], acc3[t01][3]);
            *(float4*)(out + (size_t)(r0 + t01 * 16 + c) * 16 + q * 4) = st;
        }
    }
}

extern "C" void kernel_launch(void* const* d_in, const int* in_sizes, int n_in,
                              void* d_out, int out_size, void* d_ws, size_t ws_size,
                              hipStream_t stream) {
    const float* x_cur = (const float*)d_in[0];
    const float* W1    = (const float*)d_in[1];
    const float* b1    = (const float*)d_in[2];
    const float* W2    = (const float*)d_in[3];
    const float* b2    = (const float*)d_in[4];
    const float* Bm    = (const float*)d_in[5];
    const float* Cm    = (const float*)d_in[6];
    const float* x_t   = (const float*)d_in[7];
    float* out = (float*)d_out;

    const int blocks = BATCH / 256;   // 2048 blocks x 256 rows
    andp_v11<<<blocks, 256, SMEM_BYTES, stream>>>(
        x_cur, W1, b1, W2, b2, Bm, Cm, x_t, out);
}